// Round 2
// baseline (14278.313 us; speedup 1.0000x reference)
//
#include <hip/hip_runtime.h>

#define T_DIM 512
#define B_DIM 64
#define IN_DIM 1024
#define H_DIM 2048
#define BH (B_DIM * H_DIM)   // 131072
#define KT 64                // split-K chunks in step gemm
#define KC (H_DIM / KT)      // 32

// ---------------------------------------------------------------------------
// Kernel 1: xp' = inputs @ Wi^T + bi + bh  -> out[t] slots.
// A: [32768,1024] rm, Wi: [2048,1024] rm. Tile 128x128, BK=32, 256 thr, 8x8.
// ---------------------------------------------------------------------------
__global__ __launch_bounds__(256) void irnn_xproj(
    const float* __restrict__ A, const float* __restrict__ Wi,
    const float* __restrict__ bi, const float* __restrict__ bh,
    float* __restrict__ out)
{
  __shared__ float As[32][132];
  __shared__ float Bs[32][132];
  const int tid = threadIdx.x;
  const int tx = tid & 15;
  const int ty = tid >> 4;
  const size_t row0 = (size_t)blockIdx.x * 128;
  const int    col0 = blockIdx.y * 128;
  float acc[8][8] = {};

  for (int k0 = 0; k0 < IN_DIM; k0 += 32) {
    #pragma unroll
    for (int i = 0; i < 4; ++i) {
      int f = tid + 256 * i;
      int r = f >> 3, c = f & 7;
      const float4 v = *reinterpret_cast<const float4*>(
          A + (row0 + r) * IN_DIM + k0 + c * 4);
      As[c*4+0][r] = v.x; As[c*4+1][r] = v.y;
      As[c*4+2][r] = v.z; As[c*4+3][r] = v.w;
    }
    #pragma unroll
    for (int i = 0; i < 4; ++i) {
      int f = tid + 256 * i;
      int r = f >> 3, c = f & 7;
      const float4 v = *reinterpret_cast<const float4*>(
          Wi + (size_t)(col0 + r) * IN_DIM + k0 + c * 4);
      Bs[c*4+0][r] = v.x; Bs[c*4+1][r] = v.y;
      Bs[c*4+2][r] = v.z; Bs[c*4+3][r] = v.w;
    }
    __syncthreads();
    #pragma unroll
    for (int k = 0; k < 32; ++k) {
      float a[8], b[8];
      #pragma unroll
      for (int i = 0; i < 8; i += 4)
        *reinterpret_cast<float4*>(&a[i]) =
            *reinterpret_cast<const float4*>(&As[k][ty*8 + i]);
      #pragma unroll
      for (int j = 0; j < 8; j += 4)
        *reinterpret_cast<float4*>(&b[j]) =
            *reinterpret_cast<const float4*>(&Bs[k][tx*8 + j]);
      #pragma unroll
      for (int i = 0; i < 8; ++i)
        #pragma unroll
        for (int j = 0; j < 8; ++j)
          acc[i][j] = fmaf(a[i], b[j], acc[i][j]);
    }
    __syncthreads();
  }

  float bias[8];
  #pragma unroll
  for (int j = 0; j < 8; j += 4) {
    float4 v1 = *reinterpret_cast<const float4*>(bi + col0 + tx*8 + j);
    float4 v2 = *reinterpret_cast<const float4*>(bh + col0 + tx*8 + j);
    bias[j+0] = v1.x + v2.x; bias[j+1] = v1.y + v2.y;
    bias[j+2] = v1.z + v2.z; bias[j+3] = v1.w + v2.w;
  }
  #pragma unroll
  for (int i = 0; i < 8; ++i) {
    size_t o = (row0 + ty*8 + i) * H_DIM + col0 + tx*8;
    #pragma unroll
    for (int j = 0; j < 8; j += 4) {
      float4 v;
      v.x = acc[i][j+0] + bias[j+0];
      v.y = acc[i][j+1] + bias[j+1];
      v.z = acc[i][j+2] + bias[j+2];
      v.w = acc[i][j+3] + bias[j+3];
      *reinterpret_cast<float4*>(out + o + j) = v;
    }
  }
}

// ---------------------------------------------------------------------------
// Kernel 2: WhT[k][j] = Wh[j][k]  (one-time, so step staging is coalesced)
// ---------------------------------------------------------------------------
__global__ __launch_bounds__(256) void irnn_transpose(
    const float* __restrict__ Wh, float* __restrict__ WhT)
{
  __shared__ float tile[64][68];   // 68: 16B-aligned rows, conflict-poor
  const int tid = threadIdx.x;
  const int j0 = blockIdx.x * 64;
  const int k0 = blockIdx.y * 64;
  #pragma unroll
  for (int i = 0; i < 4; ++i) {
    int f = tid + 256 * i;
    int r = f >> 4, cq = f & 15;
    float4 v = *reinterpret_cast<const float4*>(
        Wh + (size_t)(j0 + r) * H_DIM + k0 + cq * 4);
    *reinterpret_cast<float4*>(&tile[r][cq*4]) = v;
  }
  __syncthreads();
  #pragma unroll
  for (int i = 0; i < 4; ++i) {
    int f = tid + 256 * i;
    int r2 = f >> 4, c2 = f & 15;   // r2: k-row, c2: j-quad
    float4 v;
    v.x = tile[c2*4+0][r2];
    v.y = tile[c2*4+1][r2];
    v.z = tile[c2*4+2][r2];
    v.w = tile[c2*4+3][r2];
    *reinterpret_cast<float4*>(WhT + (size_t)(k0 + r2) * H_DIM + j0 + c2*4) = v;
  }
}

// ---------------------------------------------------------------------------
// Kernel 3: step GEMM partial. No LDS: W-frags stream from WhT (L2-resident),
// h-frags row-major from h_prev. Grid (8 jt, 64 kt), 256 thr, 8x8 micro.
// Thread (tm 0..7, tn 0..31) owns rows {4tm+u, 32+4tm+u}, cols {4tn+v, 128+4tn+v}.
// P[kt][b][j] += h[b, kc..kc+31] . WhT[kc.., j]
// ---------------------------------------------------------------------------
__global__ __launch_bounds__(256) void irnn_step_gemm(
    const float* __restrict__ h_prev,   // [64][2048]
    const float* __restrict__ WhT,      // [2048][2048] k-major
    float* __restrict__ P)              // [KT][64][2048]
{
  const int tid = threadIdx.x;
  const int tn = tid & 31;
  const int tm = tid >> 5;
  const int jt = blockIdx.x;            // 0..7
  const int kt = blockIdx.y;            // 0..63
  const int kc = kt * KC;
  const float* hp = h_prev + kc;
  const float* wp = WhT + (size_t)kc * H_DIM + jt * 256 + tn * 4;
  float acc[8][8] = {};

  #pragma unroll
  for (int kg = 0; kg < KC / 4; ++kg) {        // 8 groups of 4 k
    float4 hv[8];
    #pragma unroll
    for (int u = 0; u < 4; ++u) {
      hv[u]   = *reinterpret_cast<const float4*>(
          hp + (size_t)(4*tm + u) * H_DIM + kg * 4);
      hv[4+u] = *reinterpret_cast<const float4*>(
          hp + (size_t)(32 + 4*tm + u) * H_DIM + kg * 4);
    }
    float4 wv0[4], wv1[4];
    #pragma unroll
    for (int kk = 0; kk < 4; ++kk) {
      wv0[kk] = *reinterpret_cast<const float4*>(wp + (size_t)(kg*4 + kk) * H_DIM);
      wv1[kk] = *reinterpret_cast<const float4*>(wp + (size_t)(kg*4 + kk) * H_DIM + 128);
    }
    #pragma unroll
    for (int kk = 0; kk < 4; ++kk) {
      #pragma unroll
      for (int r = 0; r < 8; ++r) {
        const float hs = reinterpret_cast<const float*>(&hv[r])[kk];
        acc[r][0] = fmaf(hs, wv0[kk].x, acc[r][0]);
        acc[r][1] = fmaf(hs, wv0[kk].y, acc[r][1]);
        acc[r][2] = fmaf(hs, wv0[kk].z, acc[r][2]);
        acc[r][3] = fmaf(hs, wv0[kk].w, acc[r][3]);
        acc[r][4] = fmaf(hs, wv1[kk].x, acc[r][4]);
        acc[r][5] = fmaf(hs, wv1[kk].y, acc[r][5]);
        acc[r][6] = fmaf(hs, wv1[kk].z, acc[r][6]);
        acc[r][7] = fmaf(hs, wv1[kk].w, acc[r][7]);
      }
    }
  }

  float* pb = P + (size_t)kt * BH + jt * 256 + tn * 4;
  #pragma unroll
  for (int r = 0; r < 8; ++r) {
    const int row = (r >> 2) * 32 + 4*tm + (r & 3);
    float4 v0; v0.x = acc[r][0]; v0.y = acc[r][1]; v0.z = acc[r][2]; v0.w = acc[r][3];
    float4 v1; v1.x = acc[r][4]; v1.y = acc[r][5]; v1.z = acc[r][6]; v1.w = acc[r][7];
    *reinterpret_cast<float4*>(pb + (size_t)row * H_DIM)       = v0;
    *reinterpret_cast<float4*>(pb + (size_t)row * H_DIM + 128) = v1;
  }
}

// ---------------------------------------------------------------------------
// Kernel 4: reduce 64 partials + xp (in out[t]), relu, write out[t] (+h_last).
// ---------------------------------------------------------------------------
__global__ __launch_bounds__(128) void irnn_reduce(
    const float4* __restrict__ P4,      // [KT][32768]
    float4* __restrict__ xp_out,        // out[t] as float4, holds xp' in
    float4* __restrict__ h_last)        // out tail for t=511, else nullptr
{
  const int o4 = blockIdx.x * 128 + threadIdx.x;   // 0..32767
  float4 a = xp_out[o4];
  float sx = 0.f, sy = 0.f, sz = 0.f, sw = 0.f;
  #pragma unroll 8
  for (int kt = 0; kt < KT; ++kt) {
    const float4 p = P4[(size_t)kt * (BH/4) + o4];
    sx += p.x; sy += p.y; sz += p.z; sw += p.w;
  }
  a.x = fmaxf(a.x + sx, 0.f);
  a.y = fmaxf(a.y + sy, 0.f);
  a.z = fmaxf(a.z + sz, 0.f);
  a.w = fmaxf(a.w + sw, 0.f);
  xp_out[o4] = a;
  if (h_last) h_last[o4] = a;
}

// ---------------------------------------------------------------------------
extern "C" void kernel_launch(void* const* d_in, const int* in_sizes, int n_in,
                              void* d_out, int out_size, void* d_ws, size_t ws_size,
                              hipStream_t stream) {
  const float* inputs = (const float*)d_in[0];  // [T, B, IN] (134 MB)
  const float* hidden = (const float*)d_in[1];  // [1, B, H]
  const float* Wi     = (const float*)d_in[2];  // [H, IN]
  const float* bi     = (const float*)d_in[3];  // [H]
  const float* Wh     = (const float*)d_in[4];  // [H, H]
  const float* bh     = (const float*)d_in[5];  // [H]
  float* out = (float*)d_out;                   // [T,B,H] + [1,B,H]

  // Scratch: 32 MB partials + 16 MB WhT. Prefer d_ws; else reuse the inputs
  // buffer (dead after xproj completes; harness restores it every launch).
  float* scratch = (ws_size >= (size_t)48 * 1024 * 1024)
                       ? (float*)d_ws : (float*)d_in[0];
  float* P   = scratch;                       // [64][64][2048] = 32 MB
  float* WhT = scratch + (size_t)8 * 1024 * 1024;  // 16 MB

  // Node 1: xp' = x@Wi^T + bi + bh  (reads ALL of inputs before scratch use)
  irnn_xproj<<<dim3(256, 16), 256, 0, stream>>>(inputs, Wi, bi, bh, out);
  // Node 2: WhT = Wh^T
  irnn_transpose<<<dim3(32, 32), 256, 0, stream>>>(Wh, WhT);

  // 512 steps: split-K GEMM partials + reduce(relu) per step.
  for (int t = 0; t < T_DIM; ++t) {
    const float* hp = (t == 0) ? hidden : out + (size_t)(t - 1) * BH;
    irnn_step_gemm<<<dim3(8, KT), 256, 0, stream>>>(hp, WhT, P);
    float4* hl = (t == T_DIM - 1)
                     ? (float4*)(out + (size_t)T_DIM * BH) : nullptr;
    irnn_reduce<<<dim3(256), 128, 0, stream>>>(
        (const float4*)P, (float4*)(out + (size_t)t * BH), hl);
  }
}